// Round 19
// baseline (122.810 us; speedup 1.0000x reference)
//
#include <hip/hip_runtime.h>

typedef short short8 __attribute__((ext_vector_type(8)));
typedef short short4v __attribute__((ext_vector_type(4)));
typedef float f32x4 __attribute__((ext_vector_type(4)));
typedef float f32x16 __attribute__((ext_vector_type(16)));
typedef unsigned short ushort4v __attribute__((ext_vector_type(4)));
typedef unsigned int u32;
typedef unsigned int u32x4 __attribute__((ext_vector_type(4)));

__device__ __forceinline__ unsigned short f2b(float f) {
  unsigned u = __builtin_bit_cast(unsigned, f);
  u = u + 0x7FFFu + ((u >> 16) & 1u);   // round-to-nearest-even
  return (unsigned short)(u >> 16);
}

// Counted barriers (T4): never drain vmcnt at a barrier — prefetch loads stay
// in flight. bar_plain: ordering only. bar_lgkm: flush own LDS writes.
__device__ __forceinline__ void bar_plain() {
  __builtin_amdgcn_sched_barrier(0);
  asm volatile("" ::: "memory");
  __builtin_amdgcn_s_barrier();
  asm volatile("" ::: "memory");
  __builtin_amdgcn_sched_barrier(0);
}
__device__ __forceinline__ void bar_lgkm() {
  __builtin_amdgcn_sched_barrier(0);
  asm volatile("s_waitcnt lgkmcnt(0)" ::: "memory");
  __builtin_amdgcn_s_barrier();
  asm volatile("" ::: "memory");
  __builtin_amdgcn_sched_barrier(0);
}

// ---------------- fp32 -> bf16 convert (3 tensors, one launch) ----------------
// r16 lesson: do NOT fuse x's convert into the QKV GEMM — A is re-read by all
// 24 column-blocks; fp32-A staging doubles L2 traffic. Fusion only pays when
// the operand is read once.
__global__ void f2bf3_kernel(const float* __restrict__ a, unsigned short* __restrict__ oa, int na,
                             const float* __restrict__ b, unsigned short* __restrict__ ob, int nb,
                             const float* __restrict__ c, unsigned short* __restrict__ oc, int nc) {
  int i = blockIdx.x * blockDim.x + threadIdx.x;
  const float* in; unsigned short* out;
  if (i < na)           { in = a; out = oa; }
  else if (i < na + nb) { i -= na; in = b; out = ob; }
  else if (i < na + nb + nc) { i -= na + nb; in = c; out = oc; }
  else return;
  float4 v = reinterpret_cast<const float4*>(in)[i];
  ushort4v o;
  o.x = f2b(v.x); o.y = f2b(v.y); o.z = f2b(v.z); o.w = f2b(v.w);
  reinterpret_cast<ushort4v*>(out)[i] = o;
}

// ---------------- GEMM: C[M][N] = A[M][K] * B[N][K]^T + bias ----------------
// BM = 128 (QKV: grid 32x24 = 768 = 3/CU exact) or 64 (proj: grid 64x8 = 512
// = 2/CU exact — r16-proven).
__device__ __forceinline__ void store_out(float* C, int idx, float v) { C[idx] = v; }
__device__ __forceinline__ void store_out(short* C, int idx, float v) { C[idx] = (short)f2b(v); }

template <typename OutT, int BM>
__global__ __launch_bounds__(256, 3)
void gemm_bt_kernel(const short* __restrict__ A, const short* __restrict__ B,
                    const float* __restrict__ bias, OutT* __restrict__ C,
                    int M, int N, int K, int qcols, float qscale)
{
  constexpr int FR = BM / 32;            // A staging iters AND per-wave row-fragments
  __shared__ __align__(16) short lds_a[BM][72];
  __shared__ __align__(16) short lds_b[96][72];

  const int tid  = threadIdx.x;
  const int lane = tid & 63;
  const int wave = tid >> 6;
  const int wm   = wave >> 1;    // 2x2 waves: each (BM/2) rows x 48 cols
  const int wn   = wave & 1;
  const int r16  = lane & 15;
  const int q4   = lane >> 4;
  const int bm   = blockIdx.x;
  const int bn   = blockIdx.y;

  f32x4 zero = {0.f, 0.f, 0.f, 0.f};
  f32x4 acc[FR][3];
#pragma unroll
  for (int i = 0; i < FR; ++i)
#pragma unroll
    for (int j = 0; j < 3; ++j) acc[i][j] = zero;

  const int srow = tid >> 3;          // 0..31
  const int scol = (tid & 7) * 8;
  const short* Ab = A + (size_t)(bm * BM + srow) * K + scol;
  const short* Bb = B + (size_t)(bn * 96 + srow) * K + scol;

  short8 ar[FR], br[3];
#pragma unroll
  for (int i = 0; i < FR; ++i)
    ar[i] = *reinterpret_cast<const short8*>(Ab + i * 32 * K);
#pragma unroll
  for (int i = 0; i < 3; ++i)
    br[i] = *reinterpret_cast<const short8*>(Bb + i * 32 * K);

  const int nk = K >> 6;
  for (int kt = 0; kt < nk; ++kt) {
#pragma unroll
    for (int i = 0; i < FR; ++i)
      *reinterpret_cast<short8*>(&lds_a[srow + i * 32][scol]) = ar[i];
#pragma unroll
    for (int i = 0; i < 3; ++i)
      *reinterpret_cast<short8*>(&lds_b[srow + i * 32][scol]) = br[i];
    bar_lgkm();
    if (kt + 1 < nk) {
      const short* An = Ab + (kt + 1) * 64;
      const short* Bn = Bb + (kt + 1) * 64;
#pragma unroll
      for (int i = 0; i < FR; ++i)
        ar[i] = *reinterpret_cast<const short8*>(An + i * 32 * K);
#pragma unroll
      for (int i = 0; i < 3; ++i)
        br[i] = *reinterpret_cast<const short8*>(Bn + i * 32 * K);
    }
#pragma unroll
    for (int kk = 0; kk < 2; ++kk) {
      short8 af[FR], bf[3];
#pragma unroll
      for (int mi = 0; mi < FR; ++mi)
        af[mi] = *reinterpret_cast<const short8*>(&lds_a[wm * (BM / 2) + mi * 16 + r16][kk * 32 + q4 * 8]);
#pragma unroll
      for (int ni = 0; ni < 3; ++ni)
        bf[ni] = *reinterpret_cast<const short8*>(&lds_b[wn * 48 + ni * 16 + r16][kk * 32 + q4 * 8]);
#pragma unroll
      for (int mi = 0; mi < FR; ++mi)
#pragma unroll
        for (int ni = 0; ni < 3; ++ni)
          acc[mi][ni] = __builtin_amdgcn_mfma_f32_16x16x32_bf16(af[mi], bf[ni], acc[mi][ni], 0, 0, 0);
    }
    bar_plain();
  }

#pragma unroll
  for (int mi = 0; mi < FR; ++mi) {
    const int row0 = bm * BM + wm * (BM / 2) + mi * 16 + q4 * 4;
#pragma unroll
    for (int ni = 0; ni < 3; ++ni) {
      const int col = bn * 96 + wn * 48 + ni * 16 + r16;
      const float bz = bias[col];
      const float sc = (col < qcols) ? qscale : 1.f;
#pragma unroll
      for (int j = 0; j < 4; ++j)
        store_out(C, (row0 + j) * N + col, (acc[mi][ni][j] + bz) * sc);
    }
  }
}

// ---------------- flash attention, swapped-QK^T, in-block KV-split ----------------
// r11/r14/r15-proven structure: 4 waves/block, waves {0,1} keys [0,2048),
// {2,3} keys [2048,4096), same 64 q-rows. No online max (scores bounded, exp2
// domain, scale pre-folded into Q); l via MFMA against ones-B.
// V double-buffered; K/V LDS writes overlap softmax+PV; coalesced staging.
// r18: V scatter 8x b64 (-5.5 µs). r19: V scatter 4x b128 — each thread owns
// keys {8kg..8kg+7} x d {4kd..4kd+3}; those 8 keys fill exactly one aligned
// 16B chunk at c = kg ^ (d>>3) ^ (d&7) (same memory layout; read side
// byte-identical). COUNTED barriers (T4). Grid 64x12 = 768 = 3/CU, 12 waves/CU.
__global__ __launch_bounds__(256, 3)
void attn_kernel(const short* __restrict__ QKV, short* __restrict__ Ao)
{
  constexpr int C3 = 2304;
  __shared__ __align__(16) short k_lds[2][64][64];        // [split][key][d]
  __shared__ __align__(16) short v_lds[2][2][64][64];     // [split][buf][d][key]

  const int tid  = threadIdx.x;
  const int lane = tid & 63;
  const int wave = tid >> 6;     // 0..3
  const int sp   = wave >> 1;    // KV split
  const int qh   = wave & 1;     // q-half
  const int l31  = lane & 31;
  const int hi   = lane >> 5;
  const int swz  = l31 & 7;
  const int h    = blockIdx.y;
  const int qt   = blockIdx.x;   // 0..63

  const short* Qp = QKV + h * 64;

  // Q in registers: B-operand, col = lane&31 = q, k(d) = ks*16 + hi*8 + j
  const int qrow = qt * 64 + qh * 32 + l31;
  short8 qf[4];
#pragma unroll
  for (int ks = 0; ks < 4; ++ks)
    qf[ks] = *reinterpret_cast<const short8*>(Qp + qrow * C3 + ks * 16 + hi * 8);

  // staging roles (per split's 128 threads):
  // K: kr = row 0..15 (+16j), kc = 16B d-chunk 0..7
  const int t2 = tid & 127;
  const int kr = t2 >> 3;
  const int kc = t2 & 7;
  const int kswz = 8 * (kc ^ (kr & 7));
  // V: kg = 8-key group 0..7, kd = 4-elem d-chunk 0..15
  const int vkg = t2 >> 4;
  const int vkd = t2 & 15;

  // strength-reduced tile pointers (advance by 64*C3 per tile)
  const short* Kt = QKV + 768  + h * 64 + (size_t)(sp * 2048 + kr)      * C3 + kc * 8;
  const short* Vt = QKV + 1536 + h * 64 + (size_t)(sp * 2048 + 8 * vkg) * C3 + vkd * 4;

  short8 ka[4];
  short4v va[8];
  auto LOADT = [&]() {
#pragma unroll
    for (int j = 0; j < 4; ++j)
      ka[j] = *reinterpret_cast<const short8*>(Kt + j * 16 * C3);
#pragma unroll
    for (int j = 0; j < 8; ++j)
      va[j] = *reinterpret_cast<const short4v*>(Vt + j * C3);   // keys 8vkg..8vkg+7
    Kt += 64 * C3; Vt += 64 * C3;
  };

  short* const vw0 = &v_lds[sp][0][0][0];
  short* const vw1 = &v_lds[sp][1][0][0];
  short* vwr = vw0;   // buffer PV reads this tile
  short* vww = vw1;   // buffer WRITET fills for next tile

  auto WRITET = [&](short* vb) {
#pragma unroll
    for (int j = 0; j < 4; ++j)
      *reinterpret_cast<short8*>(&k_lds[sp][kr + 16 * j][kswz]) = ka[j];
#pragma unroll
    for (int i = 0; i < 4; ++i) {
      const int d = 4 * vkd + i;
      short8 p = {va[0][i], va[1][i], va[2][i], va[3][i],
                  va[4][i], va[5][i], va[6][i], va[7][i]};
      *reinterpret_cast<short8*>(vb + d * 64 + 8 * (vkg ^ (d >> 3) ^ (d & 7))) = p;
    }
  };

  const f32x16 ZEROv = {};
  const short ONE_BF = (short)0x3F80;
  const short8 ONESv = {ONE_BF, ONE_BF, ONE_BF, ONE_BF, ONE_BF, ONE_BF, ONE_BF, ONE_BF};

  f32x16 o0 = {}, o1 = {}, acc_l = {};

  LOADT();           // tile 0
  WRITET(vw0);       // K(0), V(0) -> buf0
  LOADT();           // issue tile 1 (stays in flight)
  bar_lgkm();        // K(0)/V(0) visible

  for (int kt = 0; kt < 32; ++kt) {
    // ---- QK^T (swapped): S^T[key][q], C-operand zero-init ----
    f32x16 s0, s1;
    {
      const short* kb0 = &k_lds[sp][l31][0];
      const short* kb1 = &k_lds[sp][l31 + 32][0];
      __builtin_amdgcn_s_setprio(1);
#pragma unroll
      for (int ks = 0; ks < 4; ++ks) {
        const int off = 8 * (((ks << 1) | hi) ^ swz);
        short8 kf0 = *reinterpret_cast<const short8*>(kb0 + off);
        short8 kf1 = *reinterpret_cast<const short8*>(kb1 + off);
        s0 = __builtin_amdgcn_mfma_f32_32x32x16_bf16(kf0, qf[ks], ks ? s0 : ZEROv, 0, 0, 0);
        s1 = __builtin_amdgcn_mfma_f32_32x32x16_bf16(kf1, qf[ks], ks ? s1 : ZEROv, 0, 0, 0);
      }
      __builtin_amdgcn_s_setprio(0);
    }
    bar_plain();                     // K(kt) reads done (program order); no drains

    if (kt != 31) {
      WRITET(vww);                   // K(kt+1), V(kt+1); counted vmcnt via data dep
      if (kt != 30) LOADT();         // issue tile kt+2; stays in flight across barriers
    }

    // ---- softmax-lite: exp2 (scores bounded; no max tracking) ----
#pragma unroll
    for (int i = 0; i < 16; ++i) {
      s0[i] = __builtin_amdgcn_exp2f(s0[i]);
      s1[i] = __builtin_amdgcn_exp2f(s1[i]);
    }

    // ---- P -> bf16 A-fragments in-register (cvt_pk + permlane32_swap) ----
    u32 pkv[4][4];
#pragma unroll
    for (int t = 0; t < 4; ++t) {
      asm("v_cvt_pk_bf16_f32 %0, %1, %2" : "=v"(pkv[0][t]) : "v"(s0[2 * t]),     "v"(s0[2 * t + 1]));
      asm("v_cvt_pk_bf16_f32 %0, %1, %2" : "=v"(pkv[1][t]) : "v"(s0[8 + 2 * t]), "v"(s0[8 + 2 * t + 1]));
      asm("v_cvt_pk_bf16_f32 %0, %1, %2" : "=v"(pkv[2][t]) : "v"(s1[2 * t]),     "v"(s1[2 * t + 1]));
      asm("v_cvt_pk_bf16_f32 %0, %1, %2" : "=v"(pkv[3][t]) : "v"(s1[8 + 2 * t]), "v"(s1[8 + 2 * t + 1]));
    }
#pragma unroll
    for (int ks = 0; ks < 4; ++ks) {
      asm("v_permlane32_swap_b32 %0, %1" : "+v"(pkv[ks][0]), "+v"(pkv[ks][2]));
      asm("v_permlane32_swap_b32 %0, %1" : "+v"(pkv[ks][1]), "+v"(pkv[ks][3]));
    }
    short8 pa[4];
#pragma unroll
    for (int ks = 0; ks < 4; ++ks) {
      u32x4 tmp = {pkv[ks][0], pkv[ks][1], pkv[ks][2], pkv[ks][3]};
      pa[ks] = __builtin_bit_cast(short8, tmp);
    }

    // ---- l row-sum on the MFMA pipe ----
#pragma unroll
    for (int ks = 0; ks < 4; ++ks)
      acc_l = __builtin_amdgcn_mfma_f32_32x32x16_bf16(pa[ks], ONESv, acc_l, 0, 0, 0);

    // ---- PV: O[q][d] += P V ----
    {
      const short* vb0 = vwr + l31 * 64;
      const short* vb1 = vwr + (l31 + 32) * 64;
      const int rsw = (l31 >> 3) ^ (l31 & 7);
      __builtin_amdgcn_s_setprio(1);
#pragma unroll
      for (int ks = 0; ks < 4; ++ks) {
        const int c = ((ks << 1) | hi) ^ rsw;
        short8 vf0 = *reinterpret_cast<const short8*>(vb0 + 8 * c);
        short8 vf1 = *reinterpret_cast<const short8*>(vb1 + 8 * (c ^ 4));
        o0 = __builtin_amdgcn_mfma_f32_32x32x16_bf16(pa[ks], vf0, o0, 0, 0, 0);
        o1 = __builtin_amdgcn_mfma_f32_32x32x16_bf16(pa[ks], vf1, o1, 0, 0, 0);
      }
      __builtin_amdgcn_s_setprio(0);
    }

    { short* t = vwr; vwr = vww; vww = t; }   // swap V buffers
    bar_lgkm();                      // WRITET(kt+1) visible; PV reads flushed;
                                     // global prefetch NOT drained
  }

  // ---- combine splits through LDS (no max shift -> plain adds) ----
  float* o_sh = (float*)&k_lds[0][0][0];      // [64][64] fp32, 16 KB
  float* l_sh = (float*)&v_lds[0][0][0][0];   // [64] fp32

  __syncthreads();
  if (sp == 1) {
#pragma unroll
    for (int r = 0; r < 16; ++r) {
      const int q = (r & 3) + 8 * (r >> 2) + 4 * hi;
      const int row = qh * 32 + q;
      o_sh[row * 64 + l31]      = o0[r];
      o_sh[row * 64 + 32 + l31] = o1[r];
    }
    if (l31 == 0) {
#pragma unroll
      for (int r = 0; r < 16; ++r) {
        const int q = (r & 3) + 8 * (r >> 2) + 4 * hi;
        l_sh[qh * 32 + q] = acc_l[r];
      }
    }
  }
  __syncthreads();
  if (sp == 0) {
#pragma unroll
    for (int r = 0; r < 16; ++r) {
      const int q = (r & 3) + 8 * (r >> 2) + 4 * hi;
      const int row = qh * 32 + q;
      const float lt = 1.f / (acc_l[r] + l_sh[row]);
      const int grow = qt * 64 + row;
      float a0 = (o0[r] + o_sh[row * 64 + l31]) * lt;
      float a1 = (o1[r] + o_sh[row * 64 + 32 + l31]) * lt;
      Ao[grow * 768 + h * 64 + l31]      = (short)f2b(a0);
      Ao[grow * 768 + h * 64 + 32 + l31] = (short)f2b(a1);
    }
  }
}

// ---------------- launch ----------------
extern "C" void kernel_launch(void* const* d_in, const int* in_sizes, int n_in,
                              void* d_out, int out_size, void* d_ws, size_t ws_size,
                              hipStream_t stream)
{
  const float* x      = (const float*)d_in[0];  // 1*64*64*768
  const float* qkv_w  = (const float*)d_in[1];  // 2304*768
  const float* qkv_b  = (const float*)d_in[2];  // 2304
  const float* proj_w = (const float*)d_in[3];  // 768*768
  const float* proj_b = (const float*)d_in[4];  // 768
  float* out = (float*)d_out;                   // 4096*768 fp32

  char* ws = (char*)d_ws;
  short* xb  = (short*)(ws + 0);           // bf16 x        [4096][768]
  short* wq  = (short*)(ws + 6291456);     // bf16 qkv_w    [2304][768]
  short* wp  = (short*)(ws + 9830400);     // bf16 proj_w   [768][768]
  short* qkv = (short*)(ws + 11010048);    // bf16 qkv out  [4096][2304]
  short* ao  = (short*)(ws + 29884416);    // bf16 attn out [4096][768]

  const float sscale = 0.125f * 1.44269504088896340736f;  // hd^-0.5 * log2(e)

  f2bf3_kernel<<<5376, 256, 0, stream>>>(x, (unsigned short*)xb, 786432,
                                         qkv_w, (unsigned short*)wq, 442368,
                                         proj_w, (unsigned short*)wp, 147456);

  gemm_bt_kernel<short, 128><<<dim3(32, 24), 256, 0, stream>>>(xb, wq, qkv_b, qkv, 4096, 2304, 768, 768, sscale);
  attn_kernel<<<dim3(64, 12), 256, 0, stream>>>(qkv, ao);
  gemm_bt_kernel<float, 64><<<dim3(64, 8), 256, 0, stream>>>(ao, wp, proj_b, out, 4096, 768, 768, 0, 1.f);
}

// Round 20
// 119.009 us; speedup vs baseline: 1.0319x; 1.0319x over previous
//
#include <hip/hip_runtime.h>

typedef short short8 __attribute__((ext_vector_type(8)));
typedef short short4v __attribute__((ext_vector_type(4)));
typedef float f32x4 __attribute__((ext_vector_type(4)));
typedef float f32x16 __attribute__((ext_vector_type(16)));
typedef unsigned short ushort4v __attribute__((ext_vector_type(4)));
typedef unsigned int u32;
typedef unsigned int u32x4 __attribute__((ext_vector_type(4)));

__device__ __forceinline__ unsigned short f2b(float f) {
  unsigned u = __builtin_bit_cast(unsigned, f);
  u = u + 0x7FFFu + ((u >> 16) & 1u);   // round-to-nearest-even
  return (unsigned short)(u >> 16);
}

// Counted barriers (T4): never drain vmcnt at a barrier — prefetch loads stay
// in flight. bar_plain: ordering only. bar_lgkm: flush own LDS writes.
__device__ __forceinline__ void bar_plain() {
  __builtin_amdgcn_sched_barrier(0);
  asm volatile("" ::: "memory");
  __builtin_amdgcn_s_barrier();
  asm volatile("" ::: "memory");
  __builtin_amdgcn_sched_barrier(0);
}
__device__ __forceinline__ void bar_lgkm() {
  __builtin_amdgcn_sched_barrier(0);
  asm volatile("s_waitcnt lgkmcnt(0)" ::: "memory");
  __builtin_amdgcn_s_barrier();
  asm volatile("" ::: "memory");
  __builtin_amdgcn_sched_barrier(0);
}

// ---------------- fp32 -> bf16 convert (3 tensors, one launch) ----------------
// r16 lesson: do NOT fuse x's convert into the QKV GEMM — A is re-read by all
// 24 column-blocks; fp32-A staging doubles L2 traffic. Fusion only pays when
// the operand is read once.
__global__ void f2bf3_kernel(const float* __restrict__ a, unsigned short* __restrict__ oa, int na,
                             const float* __restrict__ b, unsigned short* __restrict__ ob, int nb,
                             const float* __restrict__ c, unsigned short* __restrict__ oc, int nc) {
  int i = blockIdx.x * blockDim.x + threadIdx.x;
  const float* in; unsigned short* out;
  if (i < na)           { in = a; out = oa; }
  else if (i < na + nb) { i -= na; in = b; out = ob; }
  else if (i < na + nb + nc) { i -= na + nb; in = c; out = oc; }
  else return;
  float4 v = reinterpret_cast<const float4*>(in)[i];
  ushort4v o;
  o.x = f2b(v.x); o.y = f2b(v.y); o.z = f2b(v.z); o.w = f2b(v.w);
  reinterpret_cast<ushort4v*>(out)[i] = o;
}

// ---------------- GEMM: C[M][N] = A[M][K] * B[N][K]^T + bias ----------------
// BM = 128 (QKV: grid 32x24 = 768 = 3/CU exact) or 64 (proj: grid 64x8 = 512
// = 2/CU exact — r16-proven).
__device__ __forceinline__ void store_out(float* C, int idx, float v) { C[idx] = v; }
__device__ __forceinline__ void store_out(short* C, int idx, float v) { C[idx] = (short)f2b(v); }

template <typename OutT, int BM>
__global__ __launch_bounds__(256, 3)
void gemm_bt_kernel(const short* __restrict__ A, const short* __restrict__ B,
                    const float* __restrict__ bias, OutT* __restrict__ C,
                    int M, int N, int K, int qcols, float qscale)
{
  constexpr int FR = BM / 32;            // A staging iters AND per-wave row-fragments
  __shared__ __align__(16) short lds_a[BM][72];
  __shared__ __align__(16) short lds_b[96][72];

  const int tid  = threadIdx.x;
  const int lane = tid & 63;
  const int wave = tid >> 6;
  const int wm   = wave >> 1;    // 2x2 waves: each (BM/2) rows x 48 cols
  const int wn   = wave & 1;
  const int r16  = lane & 15;
  const int q4   = lane >> 4;
  const int bm   = blockIdx.x;
  const int bn   = blockIdx.y;

  f32x4 zero = {0.f, 0.f, 0.f, 0.f};
  f32x4 acc[FR][3];
#pragma unroll
  for (int i = 0; i < FR; ++i)
#pragma unroll
    for (int j = 0; j < 3; ++j) acc[i][j] = zero;

  const int srow = tid >> 3;          // 0..31
  const int scol = (tid & 7) * 8;
  const short* Ab = A + (size_t)(bm * BM + srow) * K + scol;
  const short* Bb = B + (size_t)(bn * 96 + srow) * K + scol;

  short8 ar[FR], br[3];
#pragma unroll
  for (int i = 0; i < FR; ++i)
    ar[i] = *reinterpret_cast<const short8*>(Ab + i * 32 * K);
#pragma unroll
  for (int i = 0; i < 3; ++i)
    br[i] = *reinterpret_cast<const short8*>(Bb + i * 32 * K);

  const int nk = K >> 6;
  for (int kt = 0; kt < nk; ++kt) {
#pragma unroll
    for (int i = 0; i < FR; ++i)
      *reinterpret_cast<short8*>(&lds_a[srow + i * 32][scol]) = ar[i];
#pragma unroll
    for (int i = 0; i < 3; ++i)
      *reinterpret_cast<short8*>(&lds_b[srow + i * 32][scol]) = br[i];
    bar_lgkm();
    if (kt + 1 < nk) {
      const short* An = Ab + (kt + 1) * 64;
      const short* Bn = Bb + (kt + 1) * 64;
#pragma unroll
      for (int i = 0; i < FR; ++i)
        ar[i] = *reinterpret_cast<const short8*>(An + i * 32 * K);
#pragma unroll
      for (int i = 0; i < 3; ++i)
        br[i] = *reinterpret_cast<const short8*>(Bn + i * 32 * K);
    }
#pragma unroll
    for (int kk = 0; kk < 2; ++kk) {
      short8 af[FR], bf[3];
#pragma unroll
      for (int mi = 0; mi < FR; ++mi)
        af[mi] = *reinterpret_cast<const short8*>(&lds_a[wm * (BM / 2) + mi * 16 + r16][kk * 32 + q4 * 8]);
#pragma unroll
      for (int ni = 0; ni < 3; ++ni)
        bf[ni] = *reinterpret_cast<const short8*>(&lds_b[wn * 48 + ni * 16 + r16][kk * 32 + q4 * 8]);
#pragma unroll
      for (int mi = 0; mi < FR; ++mi)
#pragma unroll
        for (int ni = 0; ni < 3; ++ni)
          acc[mi][ni] = __builtin_amdgcn_mfma_f32_16x16x32_bf16(af[mi], bf[ni], acc[mi][ni], 0, 0, 0);
    }
    bar_plain();
  }

#pragma unroll
  for (int mi = 0; mi < FR; ++mi) {
    const int row0 = bm * BM + wm * (BM / 2) + mi * 16 + q4 * 4;
#pragma unroll
    for (int ni = 0; ni < 3; ++ni) {
      const int col = bn * 96 + wn * 48 + ni * 16 + r16;
      const float bz = bias[col];
      const float sc = (col < qcols) ? qscale : 1.f;
#pragma unroll
      for (int j = 0; j < 4; ++j)
        store_out(C, (row0 + j) * N + col, (acc[mi][ni][j] + bz) * sc);
    }
  }
}

// ---------------- flash attention, swapped-QK^T, in-block KV-split ----------------
// Final proven kernel (r18, 81.5 µs): 4 waves/block, waves {0,1} keys
// [0,2048), {2,3} keys [2048,4096), same 64 q-rows. No online max (scores
// bounded, exp2 domain, scale pre-folded into Q); l via MFMA against ones-B.
// V double-buffered; K/V LDS writes overlap softmax+PV; coalesced 16B staging
// loads; V transpose scatter as 8x b64 short4v (r19 lesson: b128 scatter
// requires 8B global loads and regresses — 16B loads + b64 scatter is the
// optimum of this family). COUNTED barriers (T4): raw s_barrier, lgkm-only
// flush — global prefetch never drained at a barrier.
// Grid 64x12 = 768 blocks = 3/CU, 12 waves/CU.
__global__ __launch_bounds__(256, 3)
void attn_kernel(const short* __restrict__ QKV, short* __restrict__ Ao)
{
  constexpr int C3 = 2304;
  __shared__ __align__(16) short k_lds[2][64][64];        // [split][key][d]
  __shared__ __align__(16) short v_lds[2][2][64][64];     // [split][buf][d][key]

  const int tid  = threadIdx.x;
  const int lane = tid & 63;
  const int wave = tid >> 6;     // 0..3
  const int sp   = wave >> 1;    // KV split
  const int qh   = wave & 1;     // q-half
  const int l31  = lane & 31;
  const int hi   = lane >> 5;
  const int swz  = l31 & 7;
  const int h    = blockIdx.y;
  const int qt   = blockIdx.x;   // 0..63

  const short* Qp = QKV + h * 64;

  // Q in registers: B-operand, col = lane&31 = q, k(d) = ks*16 + hi*8 + j
  const int qrow = qt * 64 + qh * 32 + l31;
  short8 qf[4];
#pragma unroll
  for (int ks = 0; ks < 4; ++ks)
    qf[ks] = *reinterpret_cast<const short8*>(Qp + qrow * C3 + ks * 16 + hi * 8);

  // staging roles: each split's 128 threads cover its 64x64 K and V tiles (coalesced)
  const int t2 = tid & 127;
  const int kr = t2 >> 3;                  // 0..15
  const int kc = t2 & 7;                   // 16B chunk of d
  const int kswz = 8 * (kc ^ (kr & 7));

  // strength-reduced tile pointers (advance by 64*C3 per tile)
  const short* Kt = QKV + 768  + h * 64 + (size_t)(sp * 2048 + kr)     * C3 + kc * 8;
  const short* Vt = QKV + 1536 + h * 64 + (size_t)(sp * 2048 + 4 * kr) * C3 + kc * 8;

  short8 ka[4], va[4];
  auto LOADT = [&]() {
#pragma unroll
    for (int j = 0; j < 4; ++j)
      ka[j] = *reinterpret_cast<const short8*>(Kt + j * 16 * C3);
#pragma unroll
    for (int j = 0; j < 4; ++j)
      va[j] = *reinterpret_cast<const short8*>(Vt + j * C3);   // keys 4kr..4kr+3
    Kt += 64 * C3; Vt += 64 * C3;
  };

  // V-scatter constants (r12-proven algebra): stored chunk = (key>>3)^(d>>3)^(d&7),
  // offset = key&7. Keys 4kr..4kr+3: key>>3 = kr>>1, key&7 base = 4*(kr&1).
  const int vch = kr >> 1;
  const int vko = 4 * (kr & 1);

  short* const vw0 = &v_lds[sp][0][0][0];
  short* const vw1 = &v_lds[sp][1][0][0];
  short* vwr = vw0;   // buffer PV reads this tile
  short* vww = vw1;   // buffer WRITET fills for next tile

  auto WRITET = [&](short* vb) {
#pragma unroll
    for (int j = 0; j < 4; ++j)
      *reinterpret_cast<short8*>(&k_lds[sp][kr + 16 * j][kswz]) = ka[j];
#pragma unroll
    for (int i = 0; i < 8; ++i) {
      short4v p = {va[0][i], va[1][i], va[2][i], va[3][i]};
      *reinterpret_cast<short4v*>(vb + (kc * 8 + i) * 64 + 8 * (vch ^ kc ^ i) + vko) = p;
    }
  };

  const f32x16 ZEROv = {};
  const short ONE_BF = (short)0x3F80;
  const short8 ONESv = {ONE_BF, ONE_BF, ONE_BF, ONE_BF, ONE_BF, ONE_BF, ONE_BF, ONE_BF};

  f32x16 o0 = {}, o1 = {}, acc_l = {};

  LOADT();           // tile 0
  WRITET(vw0);       // K(0), V(0) -> buf0
  LOADT();           // issue tile 1 (stays in flight)
  bar_lgkm();        // K(0)/V(0) visible

  for (int kt = 0; kt < 32; ++kt) {
    // ---- QK^T (swapped): S^T[key][q], C-operand zero-init ----
    f32x16 s0, s1;
    {
      const short* kb0 = &k_lds[sp][l31][0];
      const short* kb1 = &k_lds[sp][l31 + 32][0];
      __builtin_amdgcn_s_setprio(1);
#pragma unroll
      for (int ks = 0; ks < 4; ++ks) {
        const int off = 8 * (((ks << 1) | hi) ^ swz);
        short8 kf0 = *reinterpret_cast<const short8*>(kb0 + off);
        short8 kf1 = *reinterpret_cast<const short8*>(kb1 + off);
        s0 = __builtin_amdgcn_mfma_f32_32x32x16_bf16(kf0, qf[ks], ks ? s0 : ZEROv, 0, 0, 0);
        s1 = __builtin_amdgcn_mfma_f32_32x32x16_bf16(kf1, qf[ks], ks ? s1 : ZEROv, 0, 0, 0);
      }
      __builtin_amdgcn_s_setprio(0);
    }
    bar_plain();                     // K(kt) reads done (program order); no drains

    if (kt != 31) {
      WRITET(vww);                   // K(kt+1), V(kt+1); counted vmcnt via data dep
      if (kt != 30) LOADT();         // issue tile kt+2; stays in flight across barriers
    }

    // ---- softmax-lite: exp2 (scores bounded; no max tracking) ----
#pragma unroll
    for (int i = 0; i < 16; ++i) {
      s0[i] = __builtin_amdgcn_exp2f(s0[i]);
      s1[i] = __builtin_amdgcn_exp2f(s1[i]);
    }

    // ---- P -> bf16 A-fragments in-register (cvt_pk + permlane32_swap) ----
    u32 pkv[4][4];
#pragma unroll
    for (int t = 0; t < 4; ++t) {
      asm("v_cvt_pk_bf16_f32 %0, %1, %2" : "=v"(pkv[0][t]) : "v"(s0[2 * t]),     "v"(s0[2 * t + 1]));
      asm("v_cvt_pk_bf16_f32 %0, %1, %2" : "=v"(pkv[1][t]) : "v"(s0[8 + 2 * t]), "v"(s0[8 + 2 * t + 1]));
      asm("v_cvt_pk_bf16_f32 %0, %1, %2" : "=v"(pkv[2][t]) : "v"(s1[2 * t]),     "v"(s1[2 * t + 1]));
      asm("v_cvt_pk_bf16_f32 %0, %1, %2" : "=v"(pkv[3][t]) : "v"(s1[8 + 2 * t]), "v"(s1[8 + 2 * t + 1]));
    }
#pragma unroll
    for (int ks = 0; ks < 4; ++ks) {
      asm("v_permlane32_swap_b32 %0, %1" : "+v"(pkv[ks][0]), "+v"(pkv[ks][2]));
      asm("v_permlane32_swap_b32 %0, %1" : "+v"(pkv[ks][1]), "+v"(pkv[ks][3]));
    }
    short8 pa[4];
#pragma unroll
    for (int ks = 0; ks < 4; ++ks) {
      u32x4 tmp = {pkv[ks][0], pkv[ks][1], pkv[ks][2], pkv[ks][3]};
      pa[ks] = __builtin_bit_cast(short8, tmp);
    }

    // ---- l row-sum on the MFMA pipe ----
#pragma unroll
    for (int ks = 0; ks < 4; ++ks)
      acc_l = __builtin_amdgcn_mfma_f32_32x32x16_bf16(pa[ks], ONESv, acc_l, 0, 0, 0);

    // ---- PV: O[q][d] += P V ----
    {
      const short* vb0 = vwr + l31 * 64;
      const short* vb1 = vwr + (l31 + 32) * 64;
      const int rsw = (l31 >> 3) ^ (l31 & 7);
      __builtin_amdgcn_s_setprio(1);
#pragma unroll
      for (int ks = 0; ks < 4; ++ks) {
        const int c = ((ks << 1) | hi) ^ rsw;
        short8 vf0 = *reinterpret_cast<const short8*>(vb0 + 8 * c);
        short8 vf1 = *reinterpret_cast<const short8*>(vb1 + 8 * (c ^ 4));
        o0 = __builtin_amdgcn_mfma_f32_32x32x16_bf16(pa[ks], vf0, o0, 0, 0, 0);
        o1 = __builtin_amdgcn_mfma_f32_32x32x16_bf16(pa[ks], vf1, o1, 0, 0, 0);
      }
      __builtin_amdgcn_s_setprio(0);
    }

    { short* t = vwr; vwr = vww; vww = t; }   // swap V buffers
    bar_lgkm();                      // WRITET(kt+1) visible; PV reads flushed;
                                     // global prefetch NOT drained
  }

  // ---- combine splits through LDS (no max shift -> plain adds) ----
  float* o_sh = (float*)&k_lds[0][0][0];      // [64][64] fp32, 16 KB
  float* l_sh = (float*)&v_lds[0][0][0][0];   // [64] fp32

  __syncthreads();
  if (sp == 1) {
#pragma unroll
    for (int r = 0; r < 16; ++r) {
      const int q = (r & 3) + 8 * (r >> 2) + 4 * hi;
      const int row = qh * 32 + q;
      o_sh[row * 64 + l31]      = o0[r];
      o_sh[row * 64 + 32 + l31] = o1[r];
    }
    if (l31 == 0) {
#pragma unroll
      for (int r = 0; r < 16; ++r) {
        const int q = (r & 3) + 8 * (r >> 2) + 4 * hi;
        l_sh[qh * 32 + q] = acc_l[r];
      }
    }
  }
  __syncthreads();
  if (sp == 0) {
#pragma unroll
    for (int r = 0; r < 16; ++r) {
      const int q = (r & 3) + 8 * (r >> 2) + 4 * hi;
      const int row = qh * 32 + q;
      const float lt = 1.f / (acc_l[r] + l_sh[row]);
      const int grow = qt * 64 + row;
      float a0 = (o0[r] + o_sh[row * 64 + l31]) * lt;
      float a1 = (o1[r] + o_sh[row * 64 + 32 + l31]) * lt;
      Ao[grow * 768 + h * 64 + l31]      = (short)f2b(a0);
      Ao[grow * 768 + h * 64 + 32 + l31] = (short)f2b(a1);
    }
  }
}

// ---------------- launch ----------------
extern "C" void kernel_launch(void* const* d_in, const int* in_sizes, int n_in,
                              void* d_out, int out_size, void* d_ws, size_t ws_size,
                              hipStream_t stream)
{
  const float* x      = (const float*)d_in[0];  // 1*64*64*768
  const float* qkv_w  = (const float*)d_in[1];  // 2304*768
  const float* qkv_b  = (const float*)d_in[2];  // 2304
  const float* proj_w = (const float*)d_in[3];  // 768*768
  const float* proj_b = (const float*)d_in[4];  // 768
  float* out = (float*)d_out;                   // 4096*768 fp32

  char* ws = (char*)d_ws;
  short* xb  = (short*)(ws + 0);           // bf16 x        [4096][768]
  short* wq  = (short*)(ws + 6291456);     // bf16 qkv_w    [2304][768]
  short* wp  = (short*)(ws + 9830400);     // bf16 proj_w   [768][768]
  short* qkv = (short*)(ws + 11010048);    // bf16 qkv out  [4096][2304]
  short* ao  = (short*)(ws + 29884416);    // bf16 attn out [4096][768]

  const float sscale = 0.125f * 1.44269504088896340736f;  // hd^-0.5 * log2(e)

  f2bf3_kernel<<<5376, 256, 0, stream>>>(x, (unsigned short*)xb, 786432,
                                         qkv_w, (unsigned short*)wq, 442368,
                                         proj_w, (unsigned short*)wp, 147456);

  gemm_bt_kernel<short, 128><<<dim3(32, 24), 256, 0, stream>>>(xb, wq, qkv_b, qkv, 4096, 2304, 768, 768, sscale);
  attn_kernel<<<dim3(64, 12), 256, 0, stream>>>(qkv, ao);
  gemm_bt_kernel<float, 64><<<dim3(64, 8), 256, 0, stream>>>(ao, wp, proj_b, out, 4096, 768, 768, 0, 1.f);
}